// Round 1
// baseline (269.024 us; speedup 1.0000x reference)
//
#include <hip/hip_runtime.h>

// Gated delta rule recurrence S_t = S_{t-1} @ A_t + B_t, outputs all S_t.
// T=128, B*H=64 chains, D=64. Chunked scan: K1 chunk summaries (2 matmuls/step),
// K2 scan over chunks, K3 in-chunk recurrence + output (1 matmul/step).
// fp32 VALU path (no fp32 MFMA on CDNA4). 4x4 register blocks per thread,
// 256 threads/WG, operands staged via LDS with pitch-68 padding.

constexpr int kT = 128;
constexpr int kBH = 64;       // B*H
constexpr int kD = 64;
constexpr int kNC = 8;        // chunks per chain
constexpr int kCH = kT / kNC; // 16 steps per chunk
constexpr int kP = 68;        // LDS pitch in floats (padded, 16B aligned)
constexpr int kTile = kD * kD;

__device__ __forceinline__ const float* tile_ptr(const float* base, int t, int bh) {
  return base + ((size_t)(t * kBH + bh)) * kTile;
}

// ---------------- K1: per-chunk fold (PA = prod A, PB = folded B) ----------------
__global__ __launch_bounds__(256, 2) void gdr_k1(
    const float* __restrict__ A, const float* __restrict__ Bm,
    float* __restrict__ PA, float* __restrict__ PB) {
  __shared__ float sPAT[kD * kP];  // PA transposed: sPAT[k*kP + r] = PA[r][k]
  __shared__ float sPBT[kD * kP];
  __shared__ float sA[kD * kP];    // A_t row-major, padded

  const int tid = threadIdx.x;
  const int bh = blockIdx.x >> 3;
  const int ck = blockIdx.x & 7;
  const int ti = tid >> 4, tj = tid & 15;
  const int r0 = ti << 2, c0 = tj << 2;
  const int sr = tid >> 2, sc = (tid & 3) << 4; // staging map: row sr, 16-col strip
  const int t0 = ck * kCH;

  float pa[4][4], pb[4][4];
  {
    const float* Ab = tile_ptr(A, t0, bh);
    const float* Bb = tile_ptr(Bm, t0, bh);
#pragma unroll
    for (int ii = 0; ii < 4; ++ii) {
      const float4 va = *reinterpret_cast<const float4*>(Ab + (r0 + ii) * kD + c0);
      const float4 vb = *reinterpret_cast<const float4*>(Bb + (r0 + ii) * kD + c0);
      pa[ii][0] = va.x; pa[ii][1] = va.y; pa[ii][2] = va.z; pa[ii][3] = va.w;
      pb[ii][0] = vb.x; pb[ii][1] = vb.y; pb[ii][2] = vb.z; pb[ii][3] = vb.w;
    }
  }

  float4 aq[4], bq[4];
  {
    const float* An = tile_ptr(A, t0 + 1, bh);
    const float* Bn = tile_ptr(Bm, t0 + 1, bh);
#pragma unroll
    for (int w = 0; w < 4; ++w)
      aq[w] = *reinterpret_cast<const float4*>(An + sr * kD + sc + 4 * w);
#pragma unroll
    for (int ii = 0; ii < 4; ++ii)
      bq[ii] = *reinterpret_cast<const float4*>(Bn + (r0 + ii) * kD + c0);
  }

  for (int t = t0 + 1; t < t0 + kCH; ++t) {
    if (t > t0 + 1) __syncthreads();  // WAR vs previous k-loop reads
    // transpose-write current pa/pb to LDS
#pragma unroll
    for (int jj = 0; jj < 4; ++jj) {
      *reinterpret_cast<float4*>(&sPAT[(c0 + jj) * kP + r0]) =
          make_float4(pa[0][jj], pa[1][jj], pa[2][jj], pa[3][jj]);
      *reinterpret_cast<float4*>(&sPBT[(c0 + jj) * kP + r0]) =
          make_float4(pb[0][jj], pb[1][jj], pb[2][jj], pb[3][jj]);
    }
    // stage A_t
#pragma unroll
    for (int w = 0; w < 4; ++w)
      *reinterpret_cast<float4*>(&sA[sr * kP + sc + 4 * w]) = aq[w];
    __syncthreads();

    // re-init accumulators (old values now live in LDS): pa = 0, pb = B_t
#pragma unroll
    for (int ii = 0; ii < 4; ++ii) {
      pa[ii][0] = 0.f; pa[ii][1] = 0.f; pa[ii][2] = 0.f; pa[ii][3] = 0.f;
      pb[ii][0] = bq[ii].x; pb[ii][1] = bq[ii].y; pb[ii][2] = bq[ii].z; pb[ii][3] = bq[ii].w;
    }

    // prefetch next tiles (latency hidden under k-loop)
    const int tn = (t + 1 < kT) ? t + 1 : (kT - 1);
    {
      const float* An = tile_ptr(A, tn, bh);
      const float* Bn = tile_ptr(Bm, tn, bh);
#pragma unroll
      for (int w = 0; w < 4; ++w)
        aq[w] = *reinterpret_cast<const float4*>(An + sr * kD + sc + 4 * w);
#pragma unroll
      for (int ii = 0; ii < 4; ++ii)
        bq[ii] = *reinterpret_cast<const float4*>(Bn + (r0 + ii) * kD + c0);
    }

#pragma unroll 4
    for (int k = 0; k < kD; ++k) {
      const float4 va = *reinterpret_cast<const float4*>(&sA[k * kP + c0]);
      const float4 sa = *reinterpret_cast<const float4*>(&sPAT[k * kP + r0]);
      const float4 sb = *reinterpret_cast<const float4*>(&sPBT[k * kP + r0]);
      const float af[4]  = {va.x, va.y, va.z, va.w};
      const float paf[4] = {sa.x, sa.y, sa.z, sa.w};
      const float pbf[4] = {sb.x, sb.y, sb.z, sb.w};
#pragma unroll
      for (int ii = 0; ii < 4; ++ii)
#pragma unroll
        for (int jj = 0; jj < 4; ++jj) {
          pa[ii][jj] += paf[ii] * af[jj];
          pb[ii][jj] += pbf[ii] * af[jj];
        }
    }
  }

  float* pao = PA + (size_t)blockIdx.x * kTile;
  float* pbo = PB + (size_t)blockIdx.x * kTile;
#pragma unroll
  for (int ii = 0; ii < 4; ++ii) {
    *reinterpret_cast<float4*>(pao + (r0 + ii) * kD + c0) =
        make_float4(pa[ii][0], pa[ii][1], pa[ii][2], pa[ii][3]);
    *reinterpret_cast<float4*>(pbo + (r0 + ii) * kD + c0) =
        make_float4(pb[ii][0], pb[ii][1], pb[ii][2], pb[ii][3]);
  }
}

// ---------------- K2: scan over chunk summaries -> chunk-start states ----------------
__global__ __launch_bounds__(256, 2) void gdr_k2(
    const float* __restrict__ PA, const float* __restrict__ PB,
    const float* __restrict__ S0, float* __restrict__ Sst) {
  __shared__ float sST[kD * kP];
  __shared__ float sPA[kD * kP];
  const int tid = threadIdx.x;
  const int bh = blockIdx.x;
  const int ti = tid >> 4, tj = tid & 15;
  const int r0 = ti << 2, c0 = tj << 2;
  const int sr = tid >> 2, sc = (tid & 3) << 4;

  float s[4][4];
  {
    const float* Sb = S0 + (size_t)bh * kTile;
#pragma unroll
    for (int ii = 0; ii < 4; ++ii) {
      const float4 v = *reinterpret_cast<const float4*>(Sb + (r0 + ii) * kD + c0);
      s[ii][0] = v.x; s[ii][1] = v.y; s[ii][2] = v.z; s[ii][3] = v.w;
    }
  }
  {
    float* o = Sst + (size_t)(bh * kNC) * kTile;
#pragma unroll
    for (int ii = 0; ii < 4; ++ii)
      *reinterpret_cast<float4*>(o + (r0 + ii) * kD + c0) =
          make_float4(s[ii][0], s[ii][1], s[ii][2], s[ii][3]);
  }

  for (int ck = 0; ck < kNC - 1; ++ck) {
    if (ck) __syncthreads();
#pragma unroll
    for (int jj = 0; jj < 4; ++jj)
      *reinterpret_cast<float4*>(&sST[(c0 + jj) * kP + r0]) =
          make_float4(s[0][jj], s[1][jj], s[2][jj], s[3][jj]);
    {
      const float* Pt = PA + (size_t)(bh * kNC + ck) * kTile;
#pragma unroll
      for (int w = 0; w < 4; ++w)
        *reinterpret_cast<float4*>(&sPA[sr * kP + sc + 4 * w]) =
            *reinterpret_cast<const float4*>(Pt + sr * kD + sc + 4 * w);
    }
    __syncthreads();
    {
      const float* Qt = PB + (size_t)(bh * kNC + ck) * kTile;
#pragma unroll
      for (int ii = 0; ii < 4; ++ii) {
        const float4 v = *reinterpret_cast<const float4*>(Qt + (r0 + ii) * kD + c0);
        s[ii][0] = v.x; s[ii][1] = v.y; s[ii][2] = v.z; s[ii][3] = v.w;
      }
    }
#pragma unroll 4
    for (int k = 0; k < kD; ++k) {
      const float4 va = *reinterpret_cast<const float4*>(&sPA[k * kP + c0]);
      const float4 ss = *reinterpret_cast<const float4*>(&sST[k * kP + r0]);
      const float af[4] = {va.x, va.y, va.z, va.w};
      const float sf[4] = {ss.x, ss.y, ss.z, ss.w};
#pragma unroll
      for (int ii = 0; ii < 4; ++ii)
#pragma unroll
        for (int jj = 0; jj < 4; ++jj)
          s[ii][jj] += sf[ii] * af[jj];
    }
    {
      float* o = Sst + (size_t)(bh * kNC + ck + 1) * kTile;
#pragma unroll
      for (int ii = 0; ii < 4; ++ii)
        *reinterpret_cast<float4*>(o + (r0 + ii) * kD + c0) =
            make_float4(s[ii][0], s[ii][1], s[ii][2], s[ii][3]);
    }
  }
}

// ---------------- K3: in-chunk recurrence, write all states ----------------
__global__ __launch_bounds__(256, 2) void gdr_k3(
    const float* __restrict__ A, const float* __restrict__ Bm,
    const float* __restrict__ Sst, float* __restrict__ out) {
  __shared__ float sST[kD * kP];
  __shared__ float sA[kD * kP];
  const int tid = threadIdx.x;
  const int bh = blockIdx.x >> 3;
  const int ck = blockIdx.x & 7;
  const int ti = tid >> 4, tj = tid & 15;
  const int r0 = ti << 2, c0 = tj << 2;
  const int sr = tid >> 2, sc = (tid & 3) << 4;
  const int t0 = ck * kCH;

  float s[4][4];
  {
    const float* Sb = Sst + (size_t)blockIdx.x * kTile;
#pragma unroll
    for (int ii = 0; ii < 4; ++ii) {
      const float4 v = *reinterpret_cast<const float4*>(Sb + (r0 + ii) * kD + c0);
      s[ii][0] = v.x; s[ii][1] = v.y; s[ii][2] = v.z; s[ii][3] = v.w;
    }
  }

  float4 aq[4], bq[4];
  {
    const float* An = tile_ptr(A, t0, bh);
    const float* Bn = tile_ptr(Bm, t0, bh);
#pragma unroll
    for (int w = 0; w < 4; ++w)
      aq[w] = *reinterpret_cast<const float4*>(An + sr * kD + sc + 4 * w);
#pragma unroll
    for (int ii = 0; ii < 4; ++ii)
      bq[ii] = *reinterpret_cast<const float4*>(Bn + (r0 + ii) * kD + c0);
  }

  for (int t = t0; t < t0 + kCH; ++t) {
    if (t > t0) __syncthreads();
#pragma unroll
    for (int jj = 0; jj < 4; ++jj)
      *reinterpret_cast<float4*>(&sST[(c0 + jj) * kP + r0]) =
          make_float4(s[0][jj], s[1][jj], s[2][jj], s[3][jj]);
#pragma unroll
    for (int w = 0; w < 4; ++w)
      *reinterpret_cast<float4*>(&sA[sr * kP + sc + 4 * w]) = aq[w];
    __syncthreads();

#pragma unroll
    for (int ii = 0; ii < 4; ++ii) {
      s[ii][0] = bq[ii].x; s[ii][1] = bq[ii].y; s[ii][2] = bq[ii].z; s[ii][3] = bq[ii].w;
    }
    const int tn = (t + 1 < kT) ? t + 1 : (kT - 1);
    {
      const float* An = tile_ptr(A, tn, bh);
      const float* Bn = tile_ptr(Bm, tn, bh);
#pragma unroll
      for (int w = 0; w < 4; ++w)
        aq[w] = *reinterpret_cast<const float4*>(An + sr * kD + sc + 4 * w);
#pragma unroll
      for (int ii = 0; ii < 4; ++ii)
        bq[ii] = *reinterpret_cast<const float4*>(Bn + (r0 + ii) * kD + c0);
    }

#pragma unroll 4
    for (int k = 0; k < kD; ++k) {
      const float4 va = *reinterpret_cast<const float4*>(&sA[k * kP + c0]);
      const float4 ss = *reinterpret_cast<const float4*>(&sST[k * kP + r0]);
      const float af[4] = {va.x, va.y, va.z, va.w};
      const float sf[4] = {ss.x, ss.y, ss.z, ss.w};
#pragma unroll
      for (int ii = 0; ii < 4; ++ii)
#pragma unroll
        for (int jj = 0; jj < 4; ++jj)
          s[ii][jj] += sf[ii] * af[jj];
    }

    float* o = out + ((size_t)(t * kBH + bh)) * kTile;
#pragma unroll
    for (int ii = 0; ii < 4; ++ii)
      *reinterpret_cast<float4*>(o + (r0 + ii) * kD + c0) =
          make_float4(s[ii][0], s[ii][1], s[ii][2], s[ii][3]);
  }
}

extern "C" void kernel_launch(void* const* d_in, const int* in_sizes, int n_in,
                              void* d_out, int out_size, void* d_ws, size_t ws_size,
                              hipStream_t stream) {
  const float* A  = (const float*)d_in[0];
  const float* Bm = (const float*)d_in[1];
  const float* S0 = (const float*)d_in[2];
  float* out = (float*)d_out;

  // workspace: PA [64][8][4096], PB [64][8][4096], Sstart [64][8][4096] = 24 MB
  float* PA  = (float*)d_ws;
  float* PB  = PA + (size_t)kBH * kNC * kTile;
  float* Sst = PB + (size_t)kBH * kNC * kTile;

  gdr_k1<<<dim3(kBH * kNC), dim3(256), 0, stream>>>(A, Bm, PA, PB);
  gdr_k2<<<dim3(kBH), dim3(256), 0, stream>>>(PA, PB, S0, Sst);
  gdr_k3<<<dim3(kBH * kNC), dim3(256), 0, stream>>>(A, Bm, Sst, out);
}

// Round 2
// 161.127 us; speedup vs baseline: 1.6696x; 1.6696x over previous
//
#include <hip/hip_runtime.h>

// Gated delta rule recurrence S_t = S_{t-1} @ A_t + B_t, outputs all S_t.
// T=128, B*H=64 chains, D=64. Chunked scan, kNC=8 chunks of 16 steps.
// K1/K3 use split-bf16 MFMA (hi/lo decomposition, 3 products) on the
// TRANSPOSED recurrence S^T <- A_t^T @ S^T (+ B_t^T), so the staged
// accumulator is the B-operand (contiguous-k ds_read_b128) and A_t^T is
// built by a coalesced transpose-load. K2 is the small VALU chunk-scan.

constexpr int kT = 128;
constexpr int kBH = 64;       // B*H
constexpr int kD = 64;
constexpr int kNC = 8;        // chunks per chain
constexpr int kCH = kT / kNC; // 16 steps per chunk
constexpr int kP = 68;        // LDS pitch (floats) for the VALU K2 kernel
constexpr int kTile = kD * kD;

typedef __attribute__((ext_vector_type(8))) short short8;
typedef __attribute__((ext_vector_type(4))) short short4v;
typedef __attribute__((ext_vector_type(4))) float f32x4;

__device__ __forceinline__ unsigned short f2bf(float f) {
  unsigned int u = __float_as_uint(f);
  u += 0x7FFFu + ((u >> 16) & 1u);   // round-to-nearest-even
  return (unsigned short)(u >> 16);
}
__device__ __forceinline__ float bf2f(unsigned short h) {
  return __uint_as_float(((unsigned int)h) << 16);
}
// XOR swizzle in ushort units for [64][64] bf16 planes (128B rows):
// byte ^= (row&7)<<4  ->  idx ^= (row&7)<<3. Keeps 8-elem (16B) chunks intact.
__device__ __forceinline__ int swzi(int r, int c) { return (r * 64 + c) ^ ((r & 7) << 3); }

__device__ __forceinline__ const float* tile_ptr(const float* base, int t, int bh) {
  return base + ((size_t)(t * kBH + bh)) * kTile;
}

__device__ __forceinline__ f32x4 mfma16(short8 a, short8 b, f32x4 c) {
  return __builtin_amdgcn_mfma_f32_16x16x32_bf16(a, b, c, 0, 0, 0);
}

__device__ __forceinline__ void split4(const f32x4 v, short4v& h, short4v& l) {
#pragma unroll
  for (int i = 0; i < 4; ++i) {
    const unsigned short hh = f2bf(v[i]);
    h[i] = (short)hh;
    l[i] = (short)f2bf(v[i] - bf2f(hh));
  }
}

// ---------------- K1 (MFMA): per-chunk fold (PA = prod A, PB = folded B) ----------------
__global__ __launch_bounds__(256, 2) void gdr_k1(
    const float* __restrict__ A, const float* __restrict__ Bm,
    float* __restrict__ PA, float* __restrict__ PB) {
  __shared__ unsigned short sAh[4096], sAl[4096];   // A_t^T rows (A-operand), hi/lo
  __shared__ unsigned short sPAh[4096], sPAl[4096]; // pa (normal layout), hi/lo
  __shared__ unsigned short sPBh[4096], sPBl[4096]; // pb (normal layout), hi/lo

  const int tid = threadIdx.x;
  const int lane = tid & 63, wave = tid >> 6;
  const int wr = wave >> 1, wc = wave & 1;
  const int q = lane >> 4, l15 = lane & 15;
  const int bh = blockIdx.x >> 3, ck = blockIdx.x & 7;
  const int t0 = ck * kCH;
  const int an = lane;   // A-transpose staging: this thread's A column
  const int akb = wave;  // and 16-row k-block

  // acc holds pa^T / pb^T in C/D layout: value(mi,ni,reg i) = M[b][a0+i],
  // b = wc*32+ni*16+l15 (col of acc = row of M), a0 = wr*32+mi*16+q*4.
  f32x4 apa[2][2], apb[2][2];
  {
    const float* At = tile_ptr(A, t0, bh);
    const float* Bt = tile_ptr(Bm, t0, bh);
#pragma unroll
    for (int mi = 0; mi < 2; ++mi)
#pragma unroll
      for (int ni = 0; ni < 2; ++ni) {
        const int off = (wc * 32 + ni * 16 + l15) * 64 + wr * 32 + mi * 16 + q * 4;
        apa[mi][ni] = *reinterpret_cast<const f32x4*>(At + off);  // pa = A_{t0}
        apb[mi][ni] = *reinterpret_cast<const f32x4*>(Bt + off);  // pb = B_{t0}
      }
  }

  float pfA[16];
  f32x4 pfB[2][2];
  {
    const float* At = tile_ptr(A, t0 + 1, bh);
    const float* Bt = tile_ptr(Bm, t0 + 1, bh);
#pragma unroll
    for (int kk = 0; kk < 16; ++kk) pfA[kk] = At[(akb * 16 + kk) * 64 + an];
#pragma unroll
    for (int mi = 0; mi < 2; ++mi)
#pragma unroll
      for (int ni = 0; ni < 2; ++ni)
        pfB[mi][ni] = *reinterpret_cast<const f32x4*>(
            Bt + (wc * 32 + ni * 16 + l15) * 64 + wr * 32 + mi * 16 + q * 4);
  }

  for (int t = t0 + 1; t < t0 + kCH; ++t) {
    if (t > t0 + 1) __syncthreads();  // WAR vs previous frag reads
    // stage acc (pa, pb) to LDS in normal orientation, split hi/lo
#pragma unroll
    for (int mi = 0; mi < 2; ++mi)
#pragma unroll
      for (int ni = 0; ni < 2; ++ni) {
        const int b = wc * 32 + ni * 16 + l15;
        const int a0 = wr * 32 + mi * 16 + q * 4;
        const int idx = swzi(b, a0);
        short4v h, l;
        split4(apa[mi][ni], h, l);
        *reinterpret_cast<short4v*>(&sPAh[idx]) = h;
        *reinterpret_cast<short4v*>(&sPAl[idx]) = l;
        split4(apb[mi][ni], h, l);
        *reinterpret_cast<short4v*>(&sPBh[idx]) = h;
        *reinterpret_cast<short4v*>(&sPBl[idx]) = l;
      }
    // stage A_t^T (row = A-column an, cols = k)
#pragma unroll
    for (int s = 0; s < 2; ++s) {
      short8 h, l;
#pragma unroll
      for (int j = 0; j < 8; ++j) {
        const float v = pfA[s * 8 + j];
        const unsigned short hh = f2bf(v);
        h[j] = (short)hh;
        l[j] = (short)f2bf(v - bf2f(hh));
      }
      const int idx = swzi(an, akb * 16 + s * 8);
      *reinterpret_cast<short8*>(&sAh[idx]) = h;
      *reinterpret_cast<short8*>(&sAl[idx]) = l;
    }
    __syncthreads();

    // re-init accumulators: pa = 0, pb = B_t^T
#pragma unroll
    for (int mi = 0; mi < 2; ++mi)
#pragma unroll
      for (int ni = 0; ni < 2; ++ni) {
        apa[mi][ni] = (f32x4){0.f, 0.f, 0.f, 0.f};
        apb[mi][ni] = pfB[mi][ni];
      }

    // prefetch next step (global latency hidden under MFMA phase)
    const int tn = (t + 1 < t0 + kCH) ? t + 1 : t;
    {
      const float* At = tile_ptr(A, tn, bh);
      const float* Bt = tile_ptr(Bm, tn, bh);
#pragma unroll
      for (int kk = 0; kk < 16; ++kk) pfA[kk] = At[(akb * 16 + kk) * 64 + an];
#pragma unroll
      for (int mi = 0; mi < 2; ++mi)
#pragma unroll
        for (int ni = 0; ni < 2; ++ni)
          pfB[mi][ni] = *reinterpret_cast<const f32x4*>(
              Bt + (wc * 32 + ni * 16 + l15) * 64 + wr * 32 + mi * 16 + q * 4);
    }

    // pa^T_new = A_t^T @ pa^T ; pb^T_new = A_t^T @ pb^T + B_t^T
#pragma unroll
    for (int ks = 0; ks < 2; ++ks) {
      short8 xh[2], xl[2], yah[2], yal[2], ybh[2], ybl[2];
      const int colb = ks * 32 + q * 8;
#pragma unroll
      for (int mi = 0; mi < 2; ++mi) {
        const int idx = swzi(wr * 32 + mi * 16 + l15, colb);
        xh[mi] = *reinterpret_cast<const short8*>(&sAh[idx]);
        xl[mi] = *reinterpret_cast<const short8*>(&sAl[idx]);
      }
#pragma unroll
      for (int ni = 0; ni < 2; ++ni) {
        const int idx = swzi(wc * 32 + ni * 16 + l15, colb);
        yah[ni] = *reinterpret_cast<const short8*>(&sPAh[idx]);
        yal[ni] = *reinterpret_cast<const short8*>(&sPAl[idx]);
        ybh[ni] = *reinterpret_cast<const short8*>(&sPBh[idx]);
        ybl[ni] = *reinterpret_cast<const short8*>(&sPBl[idx]);
      }
#pragma unroll
      for (int mi = 0; mi < 2; ++mi)
#pragma unroll
        for (int ni = 0; ni < 2; ++ni) {
          apa[mi][ni] = mfma16(xh[mi], yah[ni], apa[mi][ni]);
          apa[mi][ni] = mfma16(xh[mi], yal[ni], apa[mi][ni]);
          apa[mi][ni] = mfma16(xl[mi], yah[ni], apa[mi][ni]);
          apb[mi][ni] = mfma16(xh[mi], ybh[ni], apb[mi][ni]);
          apb[mi][ni] = mfma16(xh[mi], ybl[ni], apb[mi][ni]);
          apb[mi][ni] = mfma16(xl[mi], ybh[ni], apb[mi][ni]);
        }
    }
  }

  // write PA, PB in normal orientation (acc^T scatter = contiguous float4)
  float* pao = PA + (size_t)blockIdx.x * kTile;
  float* pbo = PB + (size_t)blockIdx.x * kTile;
#pragma unroll
  for (int mi = 0; mi < 2; ++mi)
#pragma unroll
    for (int ni = 0; ni < 2; ++ni) {
      const int off = (wc * 32 + ni * 16 + l15) * 64 + wr * 32 + mi * 16 + q * 4;
      *reinterpret_cast<f32x4*>(pao + off) = apa[mi][ni];
      *reinterpret_cast<f32x4*>(pbo + off) = apb[mi][ni];
    }
}

// ---------------- K2 (VALU): scan over chunk summaries -> chunk-start states ----------------
__global__ __launch_bounds__(256, 2) void gdr_k2(
    const float* __restrict__ PA, const float* __restrict__ PB,
    const float* __restrict__ S0, float* __restrict__ Sst) {
  __shared__ float sST[kD * kP];
  __shared__ float sPA[kD * kP];
  const int tid = threadIdx.x;
  const int bh = blockIdx.x;
  const int ti = tid >> 4, tj = tid & 15;
  const int r0 = ti << 2, c0 = tj << 2;
  const int sr = tid >> 2, sc = (tid & 3) << 4;

  float s[4][4];
  {
    const float* Sb = S0 + (size_t)bh * kTile;
#pragma unroll
    for (int ii = 0; ii < 4; ++ii) {
      const float4 v = *reinterpret_cast<const float4*>(Sb + (r0 + ii) * kD + c0);
      s[ii][0] = v.x; s[ii][1] = v.y; s[ii][2] = v.z; s[ii][3] = v.w;
    }
  }
  {
    float* o = Sst + (size_t)(bh * kNC) * kTile;
#pragma unroll
    for (int ii = 0; ii < 4; ++ii)
      *reinterpret_cast<float4*>(o + (r0 + ii) * kD + c0) =
          make_float4(s[ii][0], s[ii][1], s[ii][2], s[ii][3]);
  }

  for (int ck = 0; ck < kNC - 1; ++ck) {
    if (ck) __syncthreads();
#pragma unroll
    for (int jj = 0; jj < 4; ++jj)
      *reinterpret_cast<float4*>(&sST[(c0 + jj) * kP + r0]) =
          make_float4(s[0][jj], s[1][jj], s[2][jj], s[3][jj]);
    {
      const float* Pt = PA + (size_t)(bh * kNC + ck) * kTile;
#pragma unroll
      for (int w = 0; w < 4; ++w)
        *reinterpret_cast<float4*>(&sPA[sr * kP + sc + 4 * w]) =
            *reinterpret_cast<const float4*>(Pt + sr * kD + sc + 4 * w);
    }
    __syncthreads();
    {
      const float* Qt = PB + (size_t)(bh * kNC + ck) * kTile;
#pragma unroll
      for (int ii = 0; ii < 4; ++ii) {
        const float4 v = *reinterpret_cast<const float4*>(Qt + (r0 + ii) * kD + c0);
        s[ii][0] = v.x; s[ii][1] = v.y; s[ii][2] = v.z; s[ii][3] = v.w;
      }
    }
#pragma unroll 4
    for (int k = 0; k < kD; ++k) {
      const float4 va = *reinterpret_cast<const float4*>(&sPA[k * kP + c0]);
      const float4 ss = *reinterpret_cast<const float4*>(&sST[k * kP + r0]);
      const float af[4] = {va.x, va.y, va.z, va.w};
      const float sf[4] = {ss.x, ss.y, ss.z, ss.w};
#pragma unroll
      for (int ii = 0; ii < 4; ++ii)
#pragma unroll
        for (int jj = 0; jj < 4; ++jj)
          s[ii][jj] += sf[ii] * af[jj];
    }
    {
      float* o = Sst + (size_t)(bh * kNC + ck + 1) * kTile;
#pragma unroll
      for (int ii = 0; ii < 4; ++ii)
        *reinterpret_cast<float4*>(o + (r0 + ii) * kD + c0) =
            make_float4(s[ii][0], s[ii][1], s[ii][2], s[ii][3]);
    }
  }
}

// ---------------- K3 (MFMA): in-chunk recurrence, write all states ----------------
__global__ __launch_bounds__(256, 2) void gdr_k3(
    const float* __restrict__ A, const float* __restrict__ Bm,
    const float* __restrict__ Sst, float* __restrict__ out) {
  __shared__ unsigned short sAh[4096], sAl[4096];
  __shared__ unsigned short sSh[4096], sSl[4096];

  const int tid = threadIdx.x;
  const int lane = tid & 63, wave = tid >> 6;
  const int wr = wave >> 1, wc = wave & 1;
  const int q = lane >> 4, l15 = lane & 15;
  const int bh = blockIdx.x >> 3, ck = blockIdx.x & 7;
  const int t0 = ck * kCH;
  const int an = lane;
  const int akb = wave;

  f32x4 acc[2][2];  // S^T in C/D layout
  {
    const float* Sb = Sst + (size_t)blockIdx.x * kTile;
#pragma unroll
    for (int mi = 0; mi < 2; ++mi)
#pragma unroll
      for (int ni = 0; ni < 2; ++ni)
        acc[mi][ni] = *reinterpret_cast<const f32x4*>(
            Sb + (wc * 32 + ni * 16 + l15) * 64 + wr * 32 + mi * 16 + q * 4);
  }

  float pfA[16];
  f32x4 pfB[2][2];
  {
    const float* At = tile_ptr(A, t0, bh);
    const float* Bt = tile_ptr(Bm, t0, bh);
#pragma unroll
    for (int kk = 0; kk < 16; ++kk) pfA[kk] = At[(akb * 16 + kk) * 64 + an];
#pragma unroll
    for (int mi = 0; mi < 2; ++mi)
#pragma unroll
      for (int ni = 0; ni < 2; ++ni)
        pfB[mi][ni] = *reinterpret_cast<const f32x4*>(
            Bt + (wc * 32 + ni * 16 + l15) * 64 + wr * 32 + mi * 16 + q * 4);
  }

  for (int t = t0; t < t0 + kCH; ++t) {
    if (t > t0) __syncthreads();
    // stage S_prev (normal layout, split)
#pragma unroll
    for (int mi = 0; mi < 2; ++mi)
#pragma unroll
      for (int ni = 0; ni < 2; ++ni) {
        const int b = wc * 32 + ni * 16 + l15;
        const int a0 = wr * 32 + mi * 16 + q * 4;
        const int idx = swzi(b, a0);
        short4v h, l;
        split4(acc[mi][ni], h, l);
        *reinterpret_cast<short4v*>(&sSh[idx]) = h;
        *reinterpret_cast<short4v*>(&sSl[idx]) = l;
      }
    // stage A_t^T
#pragma unroll
    for (int s = 0; s < 2; ++s) {
      short8 h, l;
#pragma unroll
      for (int j = 0; j < 8; ++j) {
        const float v = pfA[s * 8 + j];
        const unsigned short hh = f2bf(v);
        h[j] = (short)hh;
        l[j] = (short)f2bf(v - bf2f(hh));
      }
      const int idx = swzi(an, akb * 16 + s * 8);
      *reinterpret_cast<short8*>(&sAh[idx]) = h;
      *reinterpret_cast<short8*>(&sAl[idx]) = l;
    }
    __syncthreads();

#pragma unroll
    for (int mi = 0; mi < 2; ++mi)
#pragma unroll
      for (int ni = 0; ni < 2; ++ni)
        acc[mi][ni] = pfB[mi][ni];  // C-init = B_t^T

    const int tn = (t + 1 < t0 + kCH) ? t + 1 : t;
    {
      const float* At = tile_ptr(A, tn, bh);
      const float* Bt = tile_ptr(Bm, tn, bh);
#pragma unroll
      for (int kk = 0; kk < 16; ++kk) pfA[kk] = At[(akb * 16 + kk) * 64 + an];
#pragma unroll
      for (int mi = 0; mi < 2; ++mi)
#pragma unroll
        for (int ni = 0; ni < 2; ++ni)
          pfB[mi][ni] = *reinterpret_cast<const f32x4*>(
              Bt + (wc * 32 + ni * 16 + l15) * 64 + wr * 32 + mi * 16 + q * 4);
    }

#pragma unroll
    for (int ks = 0; ks < 2; ++ks) {
      short8 xh[2], xl[2], yh[2], yl[2];
      const int colb = ks * 32 + q * 8;
#pragma unroll
      for (int mi = 0; mi < 2; ++mi) {
        const int idx = swzi(wr * 32 + mi * 16 + l15, colb);
        xh[mi] = *reinterpret_cast<const short8*>(&sAh[idx]);
        xl[mi] = *reinterpret_cast<const short8*>(&sAl[idx]);
      }
#pragma unroll
      for (int ni = 0; ni < 2; ++ni) {
        const int idx = swzi(wc * 32 + ni * 16 + l15, colb);
        yh[ni] = *reinterpret_cast<const short8*>(&sSh[idx]);
        yl[ni] = *reinterpret_cast<const short8*>(&sSl[idx]);
      }
#pragma unroll
      for (int mi = 0; mi < 2; ++mi)
#pragma unroll
        for (int ni = 0; ni < 2; ++ni) {
          acc[mi][ni] = mfma16(xh[mi], yh[ni], acc[mi][ni]);
          acc[mi][ni] = mfma16(xh[mi], yl[ni], acc[mi][ni]);
          acc[mi][ni] = mfma16(xl[mi], yh[ni], acc[mi][ni]);
        }
    }

    // write S_t (normal orientation)
    float* o = out + ((size_t)(t * kBH + bh)) * kTile;
#pragma unroll
    for (int mi = 0; mi < 2; ++mi)
#pragma unroll
      for (int ni = 0; ni < 2; ++ni) {
        const int off = (wc * 32 + ni * 16 + l15) * 64 + wr * 32 + mi * 16 + q * 4;
        *reinterpret_cast<f32x4*>(o + off) = acc[mi][ni];
      }
  }
}

extern "C" void kernel_launch(void* const* d_in, const int* in_sizes, int n_in,
                              void* d_out, int out_size, void* d_ws, size_t ws_size,
                              hipStream_t stream) {
  const float* A  = (const float*)d_in[0];
  const float* Bm = (const float*)d_in[1];
  const float* S0 = (const float*)d_in[2];
  float* out = (float*)d_out;

  // workspace: PA [512][4096], PB [512][4096], Sstart [512][4096] = 24 MB
  float* PA  = (float*)d_ws;
  float* PB  = PA + (size_t)kBH * kNC * kTile;
  float* Sst = PB + (size_t)kBH * kNC * kTile;

  gdr_k1<<<dim3(kBH * kNC), dim3(256), 0, stream>>>(A, Bm, PA, PB);
  gdr_k2<<<dim3(kBH), dim3(256), 0, stream>>>(PA, PB, S0, Sst);
  gdr_k3<<<dim3(kBH * kNC), dim3(256), 0, stream>>>(A, Bm, Sst, out);
}